// Round 19
// baseline (10058.541 us; speedup 1.0000x reference)
//
#include <hip/hip_runtime.h>

#define BB 32
#define TT 2048
#define HH 256
#define NT 1024

typedef unsigned long long ull;
typedef unsigned int uint;

__device__ __forceinline__ float sigm(float v) { return 1.0f / (1.0f + __expf(-v)); }

__device__ __forceinline__ int aload(const int* p) {
  return __hip_atomic_load(p, __ATOMIC_RELAXED, __HIP_MEMORY_SCOPE_AGENT);
}
__device__ __forceinline__ void astore(int* p, int v) {
  __hip_atomic_store(p, v, __ATOMIC_RELAXED, __HIP_MEMORY_SCOPE_AGENT);
}
__device__ __forceinline__ ull aload64(const ull* p) {
  return __hip_atomic_load(p, __ATOMIC_RELAXED, __HIP_MEMORY_SCOPE_AGENT);
}
__device__ __forceinline__ void astore64(ull* p, ull v) {
  __hip_atomic_store(p, v, __ATOMIC_RELAXED, __HIP_MEMORY_SCOPE_AGENT);
}

// Per-chain LDS half-barrier over 8 waves (monotone phase P; slots init 0).
// threadfence_block orders the chain's LDS staging writes before the flag store;
// sched_barrier(0)+memory clobber pin subsequent LDS reads after the spin (rule #18).
__device__ __forceinline__ void hbarrier(volatile int* s, int wsub, int lane, int P) {
    __threadfence_block();
    if (lane == 0) s[wsub] = P;
    int spins = 0;
    while (s[lane & 7] < P) { if (++spins > 8) __builtin_amdgcn_s_sleep(1); }
    __builtin_amdgcn_sched_barrier(0);
    asm volatile("" ::: "memory");
}

// Dual-chain WG: grid 256 (1 WG/CU, residency-proven), block 1024 = 2 chains x 8 waves.
// Chain 0 = layer 0 / batch-group bgA, chain 1 = layer 1 / bgA^1 (independent
// recurrences; r13's convoy was dependent layers, r18's deadlock was exact-fit
// 2-WG/CU residency — both avoided here). Communities: 32 = layer x 16 bgs (2 batches),
// 16 half-WGs x 16 cols each. Ring: 4 slots x 512 pairs {tag, hbits}, idx = bl*256+col.
// Per-thread: 2 gates x 2 batches x Kslice 32, weights 16 float4 = 64 VGPR.
// Carried: depth-4 ring, stale WAR pre-read/verify (own>=t-2, sib>=t-3), double-
// buffered LDS, x-reg prefetch, spin-then-sleep polls, conflict-free staging.
__global__ __launch_bounds__(NT) void lstm_scan(
    const float* __restrict__ x,     // [B,T,H]
    const float* __restrict__ W,     // [L,4,H,2H]
    const float* __restrict__ bias,  // [L,4,H]
    float* __restrict__ out,         // [B,T,H] + hT[B,H] + cT[B,H]
    ull* __restrict__ ring,
    int* __restrict__ sync)
{
    const int w     = blockIdx.x;     // 0..255
    const int tid   = threadIdx.x;    // 0..1023
    const int chain = tid >> 9;       // 0 or 1
    const int ct    = tid & 511;      // chain-local tid
    const int lane  = tid & 63;
    const int wsub  = ct >> 6;        // 0..7 wave within chain
    const int ks    = lane & 15;      // K-slice lane (bits 0-3)
    const int gh    = (lane >> 4) & 1;// gate pair: 0 -> {i,f}, 1 -> {o,chat}
    const int cp    = lane >> 5;      // col select (bit 5)
    const int ug    = w >> 4;         // 0..15: member index within community
    const int bgA   = w & 15;
    const int layer = chain;
    const int bg    = chain ? (bgA ^ 1) : bgA;  // chain B serves a DIFFERENT bg
    const int c     = layer * 16 + bg;
    const int col   = ug * 16 + wsub * 2 + cp;

    int* mOwn = sync + c * 16;
    int* mSib = sync + (16 + bg) * 16;             // chain A only: L1 community, same bg
    ull* ringOwn = ring + (size_t)c * 2048;        // 4 slots x 512
    ull* ringIn  = ring + (size_t)bg * 2048;       // chain B input: L0 ring, same bg

    __shared__ float inp[2][2][2][260];   // [chain][dbuf][row][col]
    __shared__ float hrec[2][2][2][260];
    __shared__ int hbar[2][8];

    if (tid < 16) hbar[tid >> 3][tid & 7] = 0;

    // weight-stationary: wA/wB[j] = W[l][gh*2 / gh*2+1][col][j*64 + ks*4 .. +3]
    float4 wA[8], wB[8];
    const float* WAp = W + (((size_t)layer * 4 + gh * 2)     * HH + col) * (2 * HH);
    const float* WBp = W + (((size_t)layer * 4 + gh * 2 + 1) * HH + col) * (2 * HH);
    #pragma unroll
    for (int j = 0; j < 8; ++j) {
        wA[j] = *(const float4*)(WAp + j * 64 + ks * 4);
        wB[j] = *(const float4*)(WBp + j * 64 + ks * 4);
    }

    float bb[4];
    #pragma unroll
    for (int g = 0; g < 4; ++g) bb[g] = bias[((size_t)layer * 4 + g) * HH + col];

    const int srow = ct >> 8;         // staging row (0/1)
    const int scol = ct & 255;        // staging col (lane-consecutive)

    // x prefetch reg (chain A): batch bg*2+srow, col scol
    float xr0 = 0.f;
    if (layer == 0) xr0 = x[(size_t)(bg * 2 + srow) * TT * HH + scol];

    __syncthreads();  // hbar init visible to all (only WG-wide barrier, outside loop)

    float c_state = 0.f;  // valid on publish lanes (gh==0 && ks<2): (bl = ks, col)
    volatile int* hb = &hbar[chain][0];

    for (int t = 0; t < TT; ++t) {
        const int p = t & 1;
        // ---- (0) WAR-gate pre-read (stale-friendly with depth-4; verified later) ----
        int gv = 0x7fffffff;
        if (ct < 16)                                 gv = aload(&mOwn[ct]);
        else if (layer == 0 && ct >= 32 && ct < 48)  gv = aload(&mSib[ct - 32]);

        // ---- (1) input stage: x from reg (chain A) or h0 ring poll (chain B) ----
        if (layer == 0) {
            inp[chain][p][srow][scol] = xr0;
            const int tn = (t + 1 < TT) ? t + 1 : t;
            xr0 = x[((size_t)(bg * 2 + srow) * TT + tn) * HH + scol];
        } else {
            const ull* rin = ringIn + (t & 3) * 512;  // h0(t), tag t+1
            const uint want = (uint)(t + 1);
            ull v0; int tries = 0;
            for (;;) {
                v0 = aload64(&rin[ct]);
                if ((uint)v0 == want) break;
                if (++tries > 4) __builtin_amdgcn_s_sleep(1);
            }
            inp[chain][p][srow][scol] = __uint_as_float((uint)(v0 >> 32));
        }
        hbarrier(hb, wsub, lane, 2 * t + 1);  // chain barrier 1: inp ready

        // ---- (2) x-part dot (K=0..255) — h(t-1) visibility hides under this ----
        float aA0 = 0.f, aA1 = 0.f, aB0 = 0.f, aB1 = 0.f;
        #pragma unroll
        for (int j = 0; j < 4; ++j) {
            const int kof = j * 64 + ks * 4;
            float4 w0 = wA[j], w1 = wB[j];
            float4 v0 = *(const float4*)&inp[chain][p][0][kof];
            float4 v1 = *(const float4*)&inp[chain][p][1][kof];
            aA0 += v0.x * w0.x + v0.y * w0.y + v0.z * w0.z + v0.w * w0.w;
            aB0 += v0.x * w1.x + v0.y * w1.y + v0.z * w1.z + v0.w * w1.w;
            aA1 += v1.x * w0.x + v1.y * w0.y + v1.z * w0.z + v1.w * w0.w;
            aB1 += v1.x * w1.x + v1.y * w1.y + v1.z * w1.z + v1.w * w1.w;
        }

        // ---- (3) recurrent poll -> hrec (slot (t-1)&3, tag t) ----
        {
            const ull* rr_ = ringOwn + ((t + 3) & 3) * 512;
            const uint want = (uint)t;
            ull v0; int tries = 0;
            for (;;) {
                v0 = aload64(&rr_[ct]);
                if ((uint)v0 == want) break;
                if (++tries > 4) __builtin_amdgcn_s_sleep(1);
            }
            hrec[chain][p][srow][scol] = __uint_as_float((uint)(v0 >> 32));
        }
        // ---- (4) WAR-gate verify (first read passes in steady state) ----
        if (ct < 16) {
            while (gv < t - 2) { __builtin_amdgcn_s_sleep(1); gv = aload(&mOwn[ct]); }
        } else if (layer == 0 && ct >= 32 && ct < 48) {
            while (gv < t - 3) { __builtin_amdgcn_s_sleep(1); gv = aload(&mSib[ct - 32]); }
        }
        hbarrier(hb, wsub, lane, 2 * t + 2);  // chain barrier 2: hrec ready + gate
        if (ct == 0) astore(&mOwn[ug], t + 1);  // staged step t (inp + hrec in LDS)

        // ---- (5) h-part dot (K=256..511) ----
        #pragma unroll
        for (int j = 4; j < 8; ++j) {
            const int kof = (j - 4) * 64 + ks * 4;
            float4 w0 = wA[j], w1 = wB[j];
            float4 v0 = *(const float4*)&hrec[chain][p][0][kof];
            float4 v1 = *(const float4*)&hrec[chain][p][1][kof];
            aA0 += v0.x * w0.x + v0.y * w0.y + v0.z * w0.z + v0.w * w0.w;
            aB0 += v0.x * w1.x + v0.y * w1.y + v0.z * w1.z + v0.w * w1.w;
            aA1 += v1.x * w0.x + v1.y * w0.y + v1.z * w0.z + v1.w * w0.w;
            aB1 += v1.x * w1.x + v1.y * w1.y + v1.z * w1.z + v1.w * w1.w;
        }

        // ---- (6) butterfly over 16 ks lanes (xor 1,2,4,8) ----
        #pragma unroll
        for (int m = 1; m <= 8; m <<= 1) {
            aA0 += __shfl_xor(aA0, m);
            aA1 += __shfl_xor(aA1, m);
            aB0 += __shfl_xor(aB0, m);
            aB1 += __shfl_xor(aB1, m);
        }
        // ---- gate-pair exchange (xor 16): on gh==0 lanes these are o,chat sums ----
        float oA0 = __shfl_xor(aA0, 16), oA1 = __shfl_xor(aA1, 16);
        float qB0 = __shfl_xor(aB0, 16), qB1 = __shfl_xor(aB1, 16);

        // ---- (7) activations + publish (lanes gh==0 && ks<2: bl = ks) ----
        if (gh == 0 && ks < 2) {
            const int bl = ks;
            float iv = ks == 0 ? aA0 : aA1;
            float fv = ks == 0 ? aB0 : aB1;
            float ov = ks == 0 ? oA0 : oA1;
            float qv = ks == 0 ? qB0 : qB1;
            float ig = sigm(iv + bb[0]);
            float fg = sigm(fv + bb[1]);
            float og = sigm(ov + bb[2]);
            float ch = tanhf(qv + bb[3]);
            c_state = fg * c_state + ig * ch;
            float hn = og * tanhf(c_state);
            astore64(&ringOwn[(t & 3) * 512 + bl * 256 + col],
                     ((ull)__float_as_uint(hn) << 32) | (ull)(uint)(t + 1));
            if (layer == 1) {
                const int bglob = bg * 2 + bl;
                out[((size_t)bglob * TT + t) * HH + col] = hn;
                if (t == TT - 1) {
                    float* tail = out + (size_t)BB * TT * HH;
                    tail[bglob * HH + col] = hn;                // hT (last layer)
                    tail[BB * HH + bglob * HH + col] = c_state; // cT (last layer)
                }
            }
        }
        // no end barrier: inp/hrec double-buffered; next step writes buffer p^1
    }
}

extern "C" void kernel_launch(void* const* d_in, const int* in_sizes, int n_in,
                              void* d_out, int out_size, void* d_ws, size_t ws_size,
                              hipStream_t stream) {
    (void)in_sizes; (void)n_in; (void)out_size; (void)ws_size;
    const float* x    = (const float*)d_in[0];
    const float* W    = (const float*)d_in[1];
    const float* bias = (const float*)d_in[2];
    float* out  = (float*)d_out;
    int*   sync = (int*)d_ws;
    ull*   ring = (ull*)((char*)d_ws + 4096);  // 32 communities x 16 KB = 512 KB

    hipMemsetAsync(d_ws, 0, 4096 + 32 * 2048 * sizeof(ull), stream);  // markers + tags
    hipLaunchKernelGGL(lstm_scan, dim3(256), dim3(NT), 0, stream, x, W, bias, out, ring, sync);
}

// Round 20
// 5993.966 us; speedup vs baseline: 1.6781x; 1.6781x over previous
//
#include <hip/hip_runtime.h>

#define BB 32
#define TT 2048
#define HH 256
#define NT 512

typedef unsigned long long ull;
typedef unsigned int uint;
typedef _Float16 half8 __attribute__((ext_vector_type(8)));
typedef float f32x4 __attribute__((ext_vector_type(4)));

__device__ __forceinline__ float sigm(float v) { return 1.0f / (1.0f + __expf(-v)); }
__device__ __forceinline__ float tanhfast(float v) {
  return 1.0f - 2.0f / (1.0f + __expf(2.0f * v));
}

__device__ __forceinline__ int aload(const int* p) {
  return __hip_atomic_load(p, __ATOMIC_RELAXED, __HIP_MEMORY_SCOPE_AGENT);
}
__device__ __forceinline__ void astore(int* p, int v) {
  __hip_atomic_store(p, v, __ATOMIC_RELAXED, __HIP_MEMORY_SCOPE_AGENT);
}
__device__ __forceinline__ ull aload64(const ull* p) {
  return __hip_atomic_load(p, __ATOMIC_RELAXED, __HIP_MEMORY_SCOPE_AGENT);
}
__device__ __forceinline__ void astore64(ull* p, ull v) {
  __hip_atomic_store(p, v, __ATOMIC_RELAXED, __HIP_MEMORY_SCOPE_AGENT);
}

// r17 shell (grid 256, communities c = layer*8+grp, 16 WGs x 16 cols x 4 batches,
// depth-4 tagged ring 4x1024 pairs {tag,hbits(f32)}, stale WAR gates, 2 barriers)
// with fp16-MFMA compute. gates[4b x 64(hid x gate)] = A[4x512] x B[512x64]:
//   waves 0-3: x-part, 8x mfma_f32_16x16x32_f16 on inpH (K=0..255), Cpart -> LDS.
//   waves 4-7: poll h(t-1)->hrecH(fp16) + WAR; after bar2: h-part MFMA, add Cpart,
//              redistribute C (4 shfl) + gate gather (3 shfl), act, publish f32.
//   waves 0-3 after bar2: stage inp(t+1) (L0 x-prefetch regs; L1 poll h0(t+1) -
//              fully overlapped with waves4-7 compute).
// Fragment layout (m89/m92/m97): A row = lane&15, k = (lane>>4)*8+i (8 contiguous);
// B col = lane&15 (= hid*4+gate sub-col), same k pattern; C col = lane&15,
// row(batch) = (lane>>4)*4+reg (batches 0-3 real, rows 4-15 garbage, ignored).
// fp16 staging quantization: pre-act err ~2e-4 << 2.83e-3 threshold (fp32 ring/state).
__global__ __launch_bounds__(NT) void lstm_scan(
    const float* __restrict__ x,     // [B,T,H]
    const float* __restrict__ W,     // [L,4,H,2H]
    const float* __restrict__ bias,  // [L,4,H]
    float* __restrict__ out,         // [B,T,H] + hT[B,H] + cT[B,H]
    ull* __restrict__ ring,
    int* __restrict__ sync)
{
    const int bid   = blockIdx.x;
    const int grp   = bid & 7;        // batch group (4 batches) == XCD slot
    const int layer = (bid >> 3) & 1;
    const int ug    = bid >> 4;       // 0..15
    const int c     = layer * 8 + grp;
    const int tid   = threadIdx.x;
    const int w     = tid >> 6;       // wave 0..7
    const int lane  = tid & 63;
    const int ntile = w & 3;          // which 16-col B tile
    const int khalf = w >> 2;         // 0: K=0..255 (x), 1: K=256..511 (h)
    const int ct    = tid & 255;      // index within wave-half
    const int n     = lane & 15;      // A row / B col / C col
    const int kseg  = lane >> 4;      // k-segment / C row group

    int* mOwn = sync + c * 16;
    int* mSib = sync + (8 + grp) * 16;             // layer-1 community, same grp
    ull* ringOwn = ring + (size_t)c * 4096;        // 4 slots x 1024
    ull* ringIn  = ring + (size_t)grp * 4096;      // layer-0 community, same grp

    __shared__ _Float16 inpH[16][264];   // rows 0-3 = batches (4-15 garbage)
    __shared__ _Float16 hrecH[16][264];
    __shared__ float cpart[256][5];      // [ntile*64+lane][4 used], stride 5 = conflict-free

    // B fragments (stationary): col n -> (hid, gate); k = khalf*256 + kb*32 + kseg*8
    const int hid  = ug * 16 + ntile * 4 + (n >> 2);
    const int gate = n & 3;
    half8 bfr[8];
    {
        const float* Wp = W + (((size_t)layer * 4 + gate) * HH + hid) * (2 * HH) + khalf * 256;
        #pragma unroll
        for (int kb = 0; kb < 8; ++kb) {
            const float* wp = Wp + kb * 32 + kseg * 8;
            half8 h;
            #pragma unroll
            for (int i = 0; i < 8; ++i) h[i] = (_Float16)wp[i];
            bfr[kb] = h;
        }
    }
    const float bb0 = bias[((size_t)layer * 4 + 0) * HH + hid];
    const float bb1 = bias[((size_t)layer * 4 + 1) * HH + hid];
    const float bb2 = bias[((size_t)layer * 4 + 2) * HH + hid];
    const float bb3 = bias[((size_t)layer * 4 + 3) * HH + hid];

    // prologue: waves 0-3 stage inp(0); L0 also prefetches x(1)
    float xr0 = 0.f, xr1 = 0.f, xr2 = 0.f, xr3 = 0.f;
    if (w < 4) {
        if (layer == 0) {
            inpH[0][ct] = (_Float16)x[((size_t)(grp * 4 + 0) * TT) * HH + ct];
            inpH[1][ct] = (_Float16)x[((size_t)(grp * 4 + 1) * TT) * HH + ct];
            inpH[2][ct] = (_Float16)x[((size_t)(grp * 4 + 2) * TT) * HH + ct];
            inpH[3][ct] = (_Float16)x[((size_t)(grp * 4 + 3) * TT) * HH + ct];
            xr0 = x[((size_t)(grp * 4 + 0) * TT + 1) * HH + ct];
            xr1 = x[((size_t)(grp * 4 + 1) * TT + 1) * HH + ct];
            xr2 = x[((size_t)(grp * 4 + 2) * TT + 1) * HH + ct];
            xr3 = x[((size_t)(grp * 4 + 3) * TT + 1) * HH + ct];
        } else {
            const ull* rin = ringIn;  // slot 0, h0(0) tag 1
            const uint want = 1u;
            ull v0, v1, v2, v3; uint pend = 0xFu; int tries = 0;
            for (;;) {
                if (pend & 1u) v0 = aload64(&rin[ct]);
                if (pend & 2u) v1 = aload64(&rin[ct + 256]);
                if (pend & 4u) v2 = aload64(&rin[ct + 512]);
                if (pend & 8u) v3 = aload64(&rin[ct + 768]);
                if ((pend & 1u) && (uint)v0 == want) { inpH[0][ct] = (_Float16)__uint_as_float((uint)(v0 >> 32)); pend &= ~1u; }
                if ((pend & 2u) && (uint)v1 == want) { inpH[1][ct] = (_Float16)__uint_as_float((uint)(v1 >> 32)); pend &= ~2u; }
                if ((pend & 4u) && (uint)v2 == want) { inpH[2][ct] = (_Float16)__uint_as_float((uint)(v2 >> 32)); pend &= ~4u; }
                if ((pend & 8u) && (uint)v3 == want) { inpH[3][ct] = (_Float16)__uint_as_float((uint)(v3 >> 32)); pend &= ~8u; }
                if (!pend) break;
                if (++tries > 4) __builtin_amdgcn_s_sleep(1);
            }
        }
    }

    float c_state = 0.f;  // valid on publish lanes (w>=4 && (n&3)==0): batch=kseg, col=hid

    for (int t = 0; t < TT; ++t) {
        __syncthreads();  // bar1: inp(t) ready
        if (w < 4) {
            // ---- x-part MFMA (K=0..255) ----
            f32x4 C = {0.f, 0.f, 0.f, 0.f};
            #pragma unroll
            for (int kb = 0; kb < 8; ++kb) {
                half8 a = *(const half8*)&inpH[n][kb * 32 + kseg * 8];
                C = __builtin_amdgcn_mfma_f32_16x16x32_f16(a, bfr[kb], C, 0, 0, 0);
            }
            float* cp = &cpart[ntile * 64 + lane][0];
            cp[0] = C[0]; cp[1] = C[1]; cp[2] = C[2]; cp[3] = C[3];
        } else {
            // ---- WAR pre-read + recurrent poll (slot (t-1)&3, tag t) ----
            int gv = 0x7fffffff;
            if (ct < 16)                                 gv = aload(&mOwn[ct]);
            else if (layer == 0 && ct >= 32 && ct < 48)  gv = aload(&mSib[ct - 32]);
            const ull* rr_ = ringOwn + ((t + 3) & 3) * 1024;
            const uint want = (uint)t;
            ull v0, v1, v2, v3; uint pend = 0xFu; int tries = 0;
            for (;;) {
                if (pend & 1u) v0 = aload64(&rr_[ct]);
                if (pend & 2u) v1 = aload64(&rr_[ct + 256]);
                if (pend & 4u) v2 = aload64(&rr_[ct + 512]);
                if (pend & 8u) v3 = aload64(&rr_[ct + 768]);
                if ((pend & 1u) && (uint)v0 == want) { hrecH[0][ct] = (_Float16)__uint_as_float((uint)(v0 >> 32)); pend &= ~1u; }
                if ((pend & 2u) && (uint)v1 == want) { hrecH[1][ct] = (_Float16)__uint_as_float((uint)(v1 >> 32)); pend &= ~2u; }
                if ((pend & 4u) && (uint)v2 == want) { hrecH[2][ct] = (_Float16)__uint_as_float((uint)(v2 >> 32)); pend &= ~4u; }
                if ((pend & 8u) && (uint)v3 == want) { hrecH[3][ct] = (_Float16)__uint_as_float((uint)(v3 >> 32)); pend &= ~8u; }
                if (!pend) break;
                if (++tries > 4) __builtin_amdgcn_s_sleep(1);
            }
            // ---- WAR verify (first read passes in steady state) ----
            if (ct < 16) {
                while (gv < t - 2) { __builtin_amdgcn_s_sleep(1); gv = aload(&mOwn[ct]); }
            } else if (layer == 0 && ct >= 32 && ct < 48) {
                while (gv < t - 3) { __builtin_amdgcn_s_sleep(1); gv = aload(&mSib[ct - 32]); }
            }
        }
        __syncthreads();  // bar2: cpart + hrec ready, gates passed
        if (tid == 0) astore(&mOwn[ug], t + 1);  // staged step t

        if (w >= 4) {
            // ---- h-part MFMA (K=256..511) + partial add ----
            f32x4 C;
            {
                const float* cp = &cpart[ntile * 64 + lane][0];
                C[0] = cp[0]; C[1] = cp[1]; C[2] = cp[2]; C[3] = cp[3];
            }
            #pragma unroll
            for (int kb = 0; kb < 8; ++kb) {
                half8 a = *(const half8*)&hrecH[n][kb * 32 + kseg * 8];
                C = __builtin_amdgcn_mfma_f32_16x16x32_f16(a, bfr[kb], C, 0, 0, 0);
            }
            // ---- redistribute: lane <- C[reg=kseg] of lane n (batches 0-3 only) ----
            float t0 = __shfl(C[0], n);
            float t1 = __shfl(C[1], n);
            float t2 = __shfl(C[2], n);
            float t3 = __shfl(C[3], n);
            float mine = kseg == 0 ? t0 : kseg == 1 ? t1 : kseg == 2 ? t2 : t3;
            // ---- gate gather: on gate-0 sub-cols, f/o/q from +1/+2/+3 ----
            float fv = __shfl_xor(mine, 1);
            float ov = __shfl_xor(mine, 2);
            float qv = __shfl_xor(mine, 3);
            if ((n & 3) == 0) {
                const int batch = kseg;
                float ig = sigm(mine + bb0);
                float fg = sigm(fv + bb1);
                float og = sigm(ov + bb2);
                float ch = tanhfast(qv + bb3);
                c_state = fg * c_state + ig * ch;
                float hn = og * tanhfast(c_state);
                astore64(&ringOwn[(t & 3) * 1024 + batch * 256 + hid],
                         ((ull)__float_as_uint(hn) << 32) | (ull)(uint)(t + 1));
                if (layer == 1) {
                    const int bglob = grp * 4 + batch;
                    out[((size_t)bglob * TT + t) * HH + hid] = hn;
                    if (t == TT - 1) {
                        float* tail = out + (size_t)BB * TT * HH;
                        tail[bglob * HH + hid] = hn;                // hT (last layer)
                        tail[BB * HH + bglob * HH + hid] = c_state; // cT (last layer)
                    }
                }
            }
        } else if (t + 1 < TT) {
            // ---- stage inp(t+1), overlapped with waves4-7 compute ----
            if (layer == 0) {
                inpH[0][ct] = (_Float16)xr0;
                inpH[1][ct] = (_Float16)xr1;
                inpH[2][ct] = (_Float16)xr2;
                inpH[3][ct] = (_Float16)xr3;
                const int tn = (t + 2 < TT) ? t + 2 : TT - 1;
                xr0 = x[((size_t)(grp * 4 + 0) * TT + tn) * HH + ct];
                xr1 = x[((size_t)(grp * 4 + 1) * TT + tn) * HH + ct];
                xr2 = x[((size_t)(grp * 4 + 2) * TT + tn) * HH + ct];
                xr3 = x[((size_t)(grp * 4 + 3) * TT + tn) * HH + ct];
            } else {
                const ull* rin = ringIn + ((t + 1) & 3) * 1024;  // h0(t+1), tag t+2
                const uint want = (uint)(t + 2);
                ull v0, v1, v2, v3; uint pend = 0xFu; int tries = 0;
                for (;;) {
                    if (pend & 1u) v0 = aload64(&rin[ct]);
                    if (pend & 2u) v1 = aload64(&rin[ct + 256]);
                    if (pend & 4u) v2 = aload64(&rin[ct + 512]);
                    if (pend & 8u) v3 = aload64(&rin[ct + 768]);
                    if ((pend & 1u) && (uint)v0 == want) { inpH[0][ct] = (_Float16)__uint_as_float((uint)(v0 >> 32)); pend &= ~1u; }
                    if ((pend & 2u) && (uint)v1 == want) { inpH[1][ct] = (_Float16)__uint_as_float((uint)(v1 >> 32)); pend &= ~2u; }
                    if ((pend & 4u) && (uint)v2 == want) { inpH[2][ct] = (_Float16)__uint_as_float((uint)(v2 >> 32)); pend &= ~4u; }
                    if ((pend & 8u) && (uint)v3 == want) { inpH[3][ct] = (_Float16)__uint_as_float((uint)(v3 >> 32)); pend &= ~8u; }
                    if (!pend) break;
                    if (++tries > 4) __builtin_amdgcn_s_sleep(1);
                }
            }
        }
    }
}

extern "C" void kernel_launch(void* const* d_in, const int* in_sizes, int n_in,
                              void* d_out, int out_size, void* d_ws, size_t ws_size,
                              hipStream_t stream) {
    (void)in_sizes; (void)n_in; (void)out_size; (void)ws_size;
    const float* x    = (const float*)d_in[0];
    const float* W    = (const float*)d_in[1];
    const float* bias = (const float*)d_in[2];
    float* out  = (float*)d_out;
    int*   sync = (int*)d_ws;
    ull*   ring = (ull*)((char*)d_ws + 4096);  // 16 communities x 32 KB = 512 KB

    hipMemsetAsync(d_ws, 0, 4096 + 16 * 4096 * sizeof(ull), stream);  // markers + tags
    hipLaunchKernelGGL(lstm_scan, dim3(256), dim3(NT), 0, stream, x, W, bias, out, ring, sync);
}